// Round 2
// baseline (19.317 us; speedup 1.0000x reference)
//
#include <hip/hip_runtime.h>

// Problem constants (B,C,H,W,L) = (4,16,256,256,25)
#define HWPIX 65536   // H*W
#define NCH   16
#define NLBL  25

// LDS weight layout: w2[k][l] holds (weight[l][2k], weight[l][2k+1]), flat
// in-matrix index o*16+c -> k = o*8 + c/2.  At a fixed k, lanes read differing
// l: bank = 2l mod 32, so only (l, l+16) alias -> 2-way conflict (measured
// free).  Same-label lanes hit the same address -> broadcast, free.
__global__ __launch_bounds__(256) void invconv_kernel(
    const float* __restrict__ x,
    const int*   __restrict__ labels,
    const float* __restrict__ weight,
    const float* __restrict__ bias,
    float*       __restrict__ out)
{
    __shared__ float2 w2[128][32];   // 32 KiB

    const int tid = threadIdx.x;

    // One pixel per thread: 262144 threads = 4096 waves = 16 waves/CU.
    const int t = blockIdx.x * 256 + tid;
    const int b = t >> 16;               // / HWPIX
    const int p = t & 65535;             // % HWPIX

    // Issue the label load and all 16 x loads BEFORE weight staging so their
    // HBM latency overlaps the staging + barrier.
    const int l0 = labels[b * HWPIX + p];

    float xv[NCH];
    const float* xb = x + b * (NCH * HWPIX) + p;
    #pragma unroll
    for (int c = 0; c < NCH; ++c)
        xv[c] = xb[c * HWPIX];           // 4B/lane, fully coalesced

    // Stage weights: flat = k*32 + l, consecutive threads take consecutive l.
    #pragma unroll
    for (int i = 0; i < 16; ++i) {
        int flat = tid + i * 256;        // < 4096
        int l = flat & 31;
        int k = flat >> 5;               // 0..127
        if (l < NLBL) {
            w2[k][l] = *reinterpret_cast<const float2*>(weight + l * 256 + k * 2);
        }
    }
    __syncthreads();

    const float bias0 = bias[l0];

    float* ob = out + b * (NCH * HWPIX) + p;
    #pragma unroll
    for (int o = 0; o < NCH; ++o) {
        float acc0 = bias0;
        #pragma unroll
        for (int c2 = 0; c2 < 8; ++c2) {
            const float2 wa = w2[o * 8 + c2][l0];
            acc0 += wa.x * xv[2 * c2] + wa.y * xv[2 * c2 + 1];
        }
        ob[o * HWPIX] = acc0;
    }
}

extern "C" void kernel_launch(void* const* d_in, const int* in_sizes, int n_in,
                              void* d_out, int out_size, void* d_ws, size_t ws_size,
                              hipStream_t stream) {
    const float* x      = (const float*)d_in[0];
    const int*   labels = (const int*)  d_in[1];
    const float* weight = (const float*)d_in[2];
    const float* bias   = (const float*)d_in[3];
    float*       out    = (float*)d_out;

    // total pixels = 4*256*256 = 262144; 1 px/thread, 256 threads/block
    dim3 grid(1024), block(256);
    invconv_kernel<<<grid, block, 0, stream>>>(x, labels, weight, bias, out);
}

// Round 3
// 14.701 us; speedup vs baseline: 1.3140x; 1.3140x over previous
//
#include <hip/hip_runtime.h>

// Problem constants (B,C,H,W,L) = (4,16,256,256,25)
#define HWPIX 65536   // H*W
#define NCH   16
#define NLBL  25

// LDS weight layout (b128): w4[k][l] = weight[l][flat 4k..4k+3] where
// flat = o*16+c, so k = o*4 + q (q = c/4).  One ds_read_b128 per (o,q,label).
// Bank of w4[k][l] = (k*128 + 4l) % 32 = 4l % 32: labels alias in groups
// {l, l+8, l+16, l+24} -> <=4 bank-words/bank per instr; unique data per
// wave-instr is <=25 labels x 16B = 400B, well under the 1024B worst case.
__global__ __launch_bounds__(256) void invconv_kernel(
    const float* __restrict__ x,
    const int*   __restrict__ labels,
    const float* __restrict__ weight,
    const float* __restrict__ bias,
    float*       __restrict__ out)
{
    __shared__ float4 w4[64][32];   // 32 KiB

    const int tid = threadIdx.x;

    // 2 consecutive pixels per thread (8B/lane HBM pattern).
    const int t = blockIdx.x * 256 + tid;
    const int P = t * 2;
    const int b = P >> 16;               // / HWPIX
    const int p = P & 65535;             // % HWPIX

    // Issue label + x loads BEFORE staging so HBM latency overlaps it.
    const int2 lab = *reinterpret_cast<const int2*>(labels + b * HWPIX + p);
    const int l0 = lab.x, l1 = lab.y;

    float2 xv[NCH];
    const float* xb = x + b * (NCH * HWPIX) + p;
    #pragma unroll
    for (int c = 0; c < NCH; ++c)
        xv[c] = *reinterpret_cast<const float2*>(xb + c * HWPIX);

    // Stage weights: 64*32 float4 slots, 25.6KB valid. flat = k*32 + l.
    #pragma unroll
    for (int i = 0; i < 8; ++i) {
        int flat = tid + i * 256;        // < 2048
        int l = flat & 31;
        int k = flat >> 5;               // 0..63
        if (l < NLBL) {
            w4[k][l] = *reinterpret_cast<const float4*>(weight + l * 256 + k * 4);
        }
    }
    __syncthreads();

    const float bias0 = bias[l0];
    const float bias1 = bias[l1];

    float* ob = out + b * (NCH * HWPIX) + p;
    #pragma unroll
    for (int o = 0; o < NCH; ++o) {
        float acc0 = bias0;
        float acc1 = bias1;
        #pragma unroll
        for (int q = 0; q < 4; ++q) {
            const float4 wa = w4[o * 4 + q][l0];
            const float4 wb = w4[o * 4 + q][l1];
            const float2 x0 = xv[4 * q + 0];
            const float2 x1 = xv[4 * q + 1];
            const float2 x2 = xv[4 * q + 2];
            const float2 x3 = xv[4 * q + 3];
            acc0 = fmaf(wa.x, x0.x, acc0);
            acc0 = fmaf(wa.y, x1.x, acc0);
            acc0 = fmaf(wa.z, x2.x, acc0);
            acc0 = fmaf(wa.w, x3.x, acc0);
            acc1 = fmaf(wb.x, x0.y, acc1);
            acc1 = fmaf(wb.y, x1.y, acc1);
            acc1 = fmaf(wb.z, x2.y, acc1);
            acc1 = fmaf(wb.w, x3.y, acc1);
        }
        *reinterpret_cast<float2*>(ob + o * HWPIX) = make_float2(acc0, acc1);
    }
}

extern "C" void kernel_launch(void* const* d_in, const int* in_sizes, int n_in,
                              void* d_out, int out_size, void* d_ws, size_t ws_size,
                              hipStream_t stream) {
    const float* x      = (const float*)d_in[0];
    const int*   labels = (const int*)  d_in[1];
    const float* weight = (const float*)d_in[2];
    const float* bias   = (const float*)d_in[3];
    float*       out    = (float*)d_out;

    // total pixels = 262144; 2 px/thread, 256 threads/block -> 512 blocks
    dim3 grid(512), block(256);
    invconv_kernel<<<grid, block, 0, stream>>>(x, labels, weight, bias, out);
}